// Round 1
// baseline (1017.308 us; speedup 1.0000x reference)
//
#include <hip/hip_runtime.h>
#include <math.h>

// EdgeConv: B=4, C=64, N=32768, k=16, O=64
// h1[b,n,k,o] = U[b,n,o] + V[b,idx[b,n,k],o]
//   U = (W1[:, :64] - W1[:, 64:]) @ x + b1      (per point)
//   V = W1[:, 64:] @ x                           (per point)
// BN is affine given stats: relu(a*h + c), a = g*rsqrt(var+eps), c = be - mean*a

#define EPSV 1e-5f
constexpr int Bb = 4;
constexpr int Cc = 64;
constexpr int Nn = 32768;
constexpr int Kk = 16;
constexpr int BN = Bb * Nn;                    // 131072
constexpr float TOTF = 2097152.0f;             // B*N*k

// ---------------- K1: U,V precompute ----------------
__global__ __launch_bounds__(256) void k_uv(const float* __restrict__ x,
                                            const float* __restrict__ W1,
                                            const float* __restrict__ b1,
                                            float* __restrict__ U,
                                            float* __restrict__ V) {
  __shared__ __align__(16) float wdT[64][64];  // [c][o] = W1[o][c]-W1[o][64+c]
  __shared__ __align__(16) float wbT[64][64];  // [c][o] = W1[o][64+c]
  __shared__ __align__(16) float xs[64][64];   // [c][p]
  int t = threadIdx.x;
  int b = blockIdx.x >> 9;                     // 512 blocks per batch (N/64)
  int n0 = (blockIdx.x & 511) << 6;

  for (int i = t; i < 4096; i += 256) {
    int o = i & 63, c = i >> 6;
    float wa = W1[o * 128 + c];
    float wb = W1[o * 128 + 64 + c];
    wdT[c][o] = wa - wb;
    wbT[c][o] = wb;
  }
  const float* xb = x + (size_t)b * Cc * Nn + n0;
  for (int i = t; i < 4096; i += 256) {
    int c = i >> 6, p = i & 63;
    xs[c][p] = xb[(size_t)c * Nn + p];
  }
  __syncthreads();

  int lane = t & 63;             // o
  int pg = t >> 6;               // wave id -> point group
  int pbase = pg * 16;
  float bv = b1[lane];
  float u[16], v[16];
#pragma unroll
  for (int j = 0; j < 16; ++j) { u[j] = bv; v[j] = 0.f; }

  for (int c = 0; c < 64; ++c) {
    float wd = wdT[c][lane];
    float wb = wbT[c][lane];
#pragma unroll
    for (int j4 = 0; j4 < 4; ++j4) {
      float4 xq = *(const float4*)&xs[c][pbase + j4 * 4];
      u[j4 * 4 + 0] += wd * xq.x; v[j4 * 4 + 0] += wb * xq.x;
      u[j4 * 4 + 1] += wd * xq.y; v[j4 * 4 + 1] += wb * xq.y;
      u[j4 * 4 + 2] += wd * xq.z; v[j4 * 4 + 2] += wb * xq.z;
      u[j4 * 4 + 3] += wd * xq.w; v[j4 * 4 + 3] += wb * xq.w;
    }
  }
  size_t base = ((size_t)b * Nn + n0 + pbase) * 64 + lane;
#pragma unroll
  for (int j = 0; j < 16; ++j) {
    U[base + (size_t)j * 64] = u[j];
    V[base + (size_t)j * 64] = v[j];
  }
}

// ---------------- K2: BN1 stats ----------------
__global__ __launch_bounds__(256) void k_stats1(const float* __restrict__ U,
                                                const float* __restrict__ V,
                                                const int* __restrict__ idx,
                                                float* __restrict__ s1,
                                                float* __restrict__ q1) {
  int t = threadIdx.x;
  int lane = t & 63, w = t >> 6;
  float s = 0.f, q = 0.f;
  for (int bn = blockIdx.x * 4 + w; bn < BN; bn += 1024 * 4) {
    int b = bn >> 15;
    float u = U[(size_t)bn * 64 + lane];
    const int* ip = idx + (size_t)bn * 16;
#pragma unroll
    for (int k4 = 0; k4 < 4; ++k4) {
      int4 i4 = ((const int4*)ip)[k4];
      int mm[4] = {i4.x, i4.y, i4.z, i4.w};
#pragma unroll
      for (int j = 0; j < 4; ++j) {
        float v = V[(((size_t)b << 15) + mm[j]) * 64 + lane];
        float h = u + v;
        s += h; q += h * h;
      }
    }
  }
  __shared__ float rs[4][64], rq[4][64];
  rs[w][lane] = s; rq[w][lane] = q;
  __syncthreads();
  if (w == 0) {
    s = rs[0][lane] + rs[1][lane] + rs[2][lane] + rs[3][lane];
    q = rq[0][lane] + rq[1][lane] + rq[2][lane] + rq[3][lane];
    atomicAdd(&s1[lane], s);
    atomicAdd(&q1[lane], q);
  }
}

// ---------------- finalize BN stats -> affine coeffs ----------------
__global__ void k_fin(const float* __restrict__ s, const float* __restrict__ q,
                      const float* __restrict__ g, const float* __restrict__ be,
                      float* __restrict__ a, float* __restrict__ c) {
  int o = threadIdx.x;
  float mean = s[o] / TOTF;
  float var = q[o] / TOTF - mean * mean;
  float av = g[o] / sqrtf(var + EPSV);
  a[o] = av;
  c[o] = be[o] - mean * av;
}

// ---------------- K4: BN2 stats (recompute relu1, matmul W2) ----------------
__global__ __launch_bounds__(256) void k_stats2(const float* __restrict__ U,
                                                const float* __restrict__ V,
                                                const int* __restrict__ idx,
                                                const float* __restrict__ a1,
                                                const float* __restrict__ c1,
                                                const float* __restrict__ W2,
                                                const float* __restrict__ b2,
                                                float* __restrict__ s2,
                                                float* __restrict__ q2) {
  __shared__ __align__(16) float rs[4][16][64];
  int t = threadIdx.x;
  int lane = t & 63, w = t >> 6;
  int b = blockIdx.x >> 9;
  int n0 = (blockIdx.x & 511) << 6;

  float4 w2r[16];
#pragma unroll
  for (int i = 0; i < 16; ++i) w2r[i] = *(const float4*)(W2 + lane * 64 + i * 4);
  float av = a1[lane], cv = c1[lane], b2v = b2[lane];
  float s = 0.f, q = 0.f;

  for (int pt = 0; pt < 16; ++pt) {
    int bn = b * Nn + n0 + w * 16 + pt;
    float u = U[(size_t)bn * 64 + lane];
    const int* ip = idx + (size_t)bn * 16;
#pragma unroll
    for (int k4 = 0; k4 < 4; ++k4) {
      int4 i4 = ((const int4*)ip)[k4];
      int mm[4] = {i4.x, i4.y, i4.z, i4.w};
#pragma unroll
      for (int j = 0; j < 4; ++j) {
        float v = V[(((size_t)b * Nn) + mm[j]) * 64 + lane];
        rs[w][k4 * 4 + j][lane] = fmaxf(av * (u + v) + cv, 0.f);
      }
    }
#pragma unroll 4
    for (int k = 0; k < 16; ++k) {
      float acc = b2v;
#pragma unroll
      for (int o4 = 0; o4 < 16; ++o4) {
        float4 r4 = *(const float4*)&rs[w][k][o4 * 4];
        acc += w2r[o4].x * r4.x;
        acc += w2r[o4].y * r4.y;
        acc += w2r[o4].z * r4.z;
        acc += w2r[o4].w * r4.w;
      }
      s += acc; q += acc * acc;
    }
  }
  __shared__ float red[4][64];
  red[w][lane] = s;
  __syncthreads();
  if (w == 0) {
    s = red[0][lane] + red[1][lane] + red[2][lane] + red[3][lane];
    atomicAdd(&s2[lane], s);
  }
  __syncthreads();
  red[w][lane] = q;
  __syncthreads();
  if (w == 0) {
    q = red[0][lane] + red[1][lane] + red[2][lane] + red[3][lane];
    atomicAdd(&q2[lane], q);
  }
}

// ---------------- K6: final output ----------------
__global__ __launch_bounds__(256) void k_final(const float* __restrict__ U,
                                               const float* __restrict__ V,
                                               const int* __restrict__ idx,
                                               const float* __restrict__ a1,
                                               const float* __restrict__ c1,
                                               const float* __restrict__ W2,
                                               const float* __restrict__ b2,
                                               const float* __restrict__ a2,
                                               const float* __restrict__ c2,
                                               float* __restrict__ out) {
  __shared__ __align__(16) float rs[4][16][64];
  __shared__ float om[64][65];   // [p][pt], padded
  int t = threadIdx.x;
  int lane = t & 63, w = t >> 6;
  int b = blockIdx.x >> 9;
  int n0 = (blockIdx.x & 511) << 6;

  float4 w2r[16];
#pragma unroll
  for (int i = 0; i < 16; ++i) w2r[i] = *(const float4*)(W2 + lane * 64 + i * 4);
  float av = a1[lane], cv = c1[lane], b2v = b2[lane];
  float a2v = a2[lane], c2v = c2[lane];

  for (int pt = 0; pt < 16; ++pt) {
    int bn = b * Nn + n0 + w * 16 + pt;
    float u = U[(size_t)bn * 64 + lane];
    const int* ip = idx + (size_t)bn * 16;
#pragma unroll
    for (int k4 = 0; k4 < 4; ++k4) {
      int4 i4 = ((const int4*)ip)[k4];
      int mm[4] = {i4.x, i4.y, i4.z, i4.w};
#pragma unroll
      for (int j = 0; j < 4; ++j) {
        float v = V[(((size_t)b * Nn) + mm[j]) * 64 + lane];
        rs[w][k4 * 4 + j][lane] = fmaxf(av * (u + v) + cv, 0.f);
      }
    }
    float m = 0.f;  // relu output >= 0, so max >= 0
#pragma unroll 4
    for (int k = 0; k < 16; ++k) {
      float acc = b2v;
#pragma unroll
      for (int o4 = 0; o4 < 16; ++o4) {
        float4 r4 = *(const float4*)&rs[w][k][o4 * 4];
        acc += w2r[o4].x * r4.x;
        acc += w2r[o4].y * r4.y;
        acc += w2r[o4].z * r4.z;
        acc += w2r[o4].w * r4.w;
      }
      m = fmaxf(m, fmaxf(a2v * acc + c2v, 0.f));
    }
    om[lane][w * 16 + pt] = m;
  }
  __syncthreads();
  for (int i = t; i < 4096; i += 256) {
    int p = i >> 6, pc = i & 63;
    out[((size_t)b * 64 + p) * Nn + n0 + pc] = om[p][pc];
  }
}

extern "C" void kernel_launch(void* const* d_in, const int* in_sizes, int n_in,
                              void* d_out, int out_size, void* d_ws, size_t ws_size,
                              hipStream_t stream) {
  const float* x   = (const float*)d_in[0];
  const int*   idx = (const int*)d_in[1];
  const float* W1  = (const float*)d_in[2];
  const float* b1  = (const float*)d_in[3];
  const float* g1  = (const float*)d_in[4];
  const float* be1 = (const float*)d_in[5];
  const float* W2  = (const float*)d_in[6];
  const float* b2  = (const float*)d_in[7];
  const float* g2  = (const float*)d_in[8];
  const float* be2 = (const float*)d_in[9];
  float* out = (float*)d_out;

  float* U  = (float*)d_ws;                  // 32 MB
  float* V  = U + (size_t)BN * 64;           // 32 MB
  float* st = V + (size_t)BN * 64;           // stats scratch
  float* s1 = st,       *q1 = st + 64,  *a1 = st + 128, *c1 = st + 192;
  float* s2 = st + 256, *q2 = st + 320, *a2 = st + 384, *c2 = st + 448;

  hipMemsetAsync(st, 0, 512 * sizeof(float), stream);
  k_uv<<<2048, 256, 0, stream>>>(x, W1, b1, U, V);
  k_stats1<<<1024, 256, 0, stream>>>(U, V, idx, s1, q1);
  k_fin<<<1, 64, 0, stream>>>(s1, q1, g1, be1, a1, c1);
  k_stats2<<<2048, 256, 0, stream>>>(U, V, idx, a1, c1, W2, b2, s2, q2);
  k_fin<<<1, 64, 0, stream>>>(s2, q2, g2, be2, a2, c2);
  k_final<<<2048, 256, 0, stream>>>(U, V, idx, a1, c1, W2, b2, a2, c2, out);
}

// Round 2
// 465.933 us; speedup vs baseline: 2.1834x; 2.1834x over previous
//
#include <hip/hip_runtime.h>
#include <math.h>

// EdgeConv: B=4, C=64, N=32768, k=16, O=64
// h1[b,n,k,o] = U[b,n,o] + V[b,idx[b,n,k],o]
//   U = (W1[:, :64] - W1[:, 64:]) @ x + b1
//   V = W1[:, 64:] @ x
// BN affine given stats: relu(a*h + c), a = g*rsqrt(var+eps), c = be - mean*a
// Layer 2 (h2 = relu1 @ W2^T) via bf16 MFMA 16x16x32: one point's 16 neighbors
// = one 16-row tile; max-over-k and sum-stats are row-order-invariant.

#define EPSV 1e-5f
constexpr int Bb = 4;
constexpr int Cc = 64;
constexpr int Nn = 32768;
constexpr int BN = Bb * Nn;                    // 131072
constexpr float TOTF = 2097152.0f;             // B*N*k

typedef __attribute__((ext_vector_type(8))) short short8;
typedef __attribute__((ext_vector_type(4))) float floatx4;

__device__ __forceinline__ short f2bf(float f) {
  union { float f; unsigned u; } un; un.f = f;
  unsigned r = un.u + 0x7FFF + ((un.u >> 16) & 1);   // RNE
  return (short)(r >> 16);
}

// ---------------- K1: U,V precompute ----------------
__global__ __launch_bounds__(256) void k_uv(const float* __restrict__ x,
                                            const float* __restrict__ W1,
                                            const float* __restrict__ b1,
                                            float* __restrict__ U,
                                            float* __restrict__ V) {
  __shared__ __align__(16) float wdT[64][64];
  __shared__ __align__(16) float wbT[64][64];
  __shared__ __align__(16) float xs[64][64];
  int t = threadIdx.x;
  int b = blockIdx.x >> 9;
  int n0 = (blockIdx.x & 511) << 6;

  for (int i = t; i < 4096; i += 256) {
    int o = i & 63, c = i >> 6;
    float wa = W1[o * 128 + c];
    float wb = W1[o * 128 + 64 + c];
    wdT[c][o] = wa - wb;
    wbT[c][o] = wb;
  }
  const float* xb = x + (size_t)b * Cc * Nn + n0;
  for (int i = t; i < 4096; i += 256) {
    int c = i >> 6, p = i & 63;
    xs[c][p] = xb[(size_t)c * Nn + p];
  }
  __syncthreads();

  int lane = t & 63;
  int pg = t >> 6;
  int pbase = pg * 16;
  float bv = b1[lane];
  float u[16], v[16];
#pragma unroll
  for (int j = 0; j < 16; ++j) { u[j] = bv; v[j] = 0.f; }

  for (int c = 0; c < 64; ++c) {
    float wd = wdT[c][lane];
    float wb = wbT[c][lane];
#pragma unroll
    for (int j4 = 0; j4 < 4; ++j4) {
      float4 xq = *(const float4*)&xs[c][pbase + j4 * 4];
      u[j4 * 4 + 0] += wd * xq.x; v[j4 * 4 + 0] += wb * xq.x;
      u[j4 * 4 + 1] += wd * xq.y; v[j4 * 4 + 1] += wb * xq.y;
      u[j4 * 4 + 2] += wd * xq.z; v[j4 * 4 + 2] += wb * xq.z;
      u[j4 * 4 + 3] += wd * xq.w; v[j4 * 4 + 3] += wb * xq.w;
    }
  }
  size_t base = ((size_t)b * Nn + n0 + pbase) * 64 + lane;
#pragma unroll
  for (int j = 0; j < 16; ++j) {
    U[base + (size_t)j * 64] = u[j];
    V[base + (size_t)j * 64] = v[j];
  }
}

// ---------------- K2: BN1 stats (gather) ----------------
__global__ __launch_bounds__(256) void k_stats1(const float* __restrict__ U,
                                                const float* __restrict__ V,
                                                const int* __restrict__ idx,
                                                float* __restrict__ s1,
                                                float* __restrict__ q1) {
  int t = threadIdx.x;
  int lane = t & 63, w = t >> 6;
  float s = 0.f, q = 0.f;
  for (int bn = blockIdx.x * 4 + w; bn < BN; bn += 1024 * 4) {
    int b = bn >> 15;
    float u = U[(size_t)bn * 64 + lane];
    const int* ip = idx + (size_t)bn * 16;
#pragma unroll
    for (int k4 = 0; k4 < 4; ++k4) {
      int4 i4 = ((const int4*)ip)[k4];
      int mm[4] = {i4.x, i4.y, i4.z, i4.w};
#pragma unroll
      for (int j = 0; j < 4; ++j) {
        float v = V[(((size_t)b << 15) + mm[j]) * 64 + lane];
        float h = u + v;
        s += h; q += h * h;
      }
    }
  }
  __shared__ float rs[4][64], rq[4][64];
  rs[w][lane] = s; rq[w][lane] = q;
  __syncthreads();
  if (w == 0) {
    s = rs[0][lane] + rs[1][lane] + rs[2][lane] + rs[3][lane];
    q = rq[0][lane] + rq[1][lane] + rq[2][lane] + rq[3][lane];
    atomicAdd(&s1[lane], s);
    atomicAdd(&q1[lane], q);
  }
}

// ---------------- finalize BN1 ----------------
__global__ void k_fin(const float* __restrict__ s, const float* __restrict__ q,
                      const float* __restrict__ g, const float* __restrict__ be,
                      float* __restrict__ a, float* __restrict__ c) {
  int o = threadIdx.x;
  float mean = s[o] / TOTF;
  float var = q[o] / TOTF - mean * mean;
  float av = g[o] / sqrtf(var + EPSV);
  a[o] = av;
  c[o] = be[o] - mean * av;
}

// -------- shared frag builder: gather U+V, BN1+relu, pack bf16 A-frags --------
__device__ __forceinline__ void build_frags(const float* __restrict__ U,
                                            const float* __restrict__ V,
                                            const int* __restrict__ idx,
                                            size_t bnP, size_t bbase,
                                            int g, int r,
                                            const float* a1v, const float* c1v,
                                            short8& fa0, short8& fa1) {
  int j = idx[bnP * 16 + r];                       // this lane's neighbor (k = r)
  const float* vp = V + (bbase + (size_t)j) * 64;
  const float* up = U + bnP * 64;
  int o0 = g * 8;
  float4 va = *(const float4*)(vp + o0);
  float4 vb = *(const float4*)(vp + o0 + 4);
  float4 vc = *(const float4*)(vp + o0 + 32);
  float4 vd = *(const float4*)(vp + o0 + 36);
  float4 ua = *(const float4*)(up + o0);
  float4 ub = *(const float4*)(up + o0 + 4);
  float4 uc = *(const float4*)(up + o0 + 32);
  float4 ud = *(const float4*)(up + o0 + 36);
  float h[16];
  h[0] = ua.x + va.x;  h[1] = ua.y + va.y;  h[2] = ua.z + va.z;  h[3] = ua.w + va.w;
  h[4] = ub.x + vb.x;  h[5] = ub.y + vb.y;  h[6] = ub.z + vb.z;  h[7] = ub.w + vb.w;
  h[8] = uc.x + vc.x;  h[9] = uc.y + vc.y;  h[10] = uc.z + vc.z; h[11] = uc.w + vc.w;
  h[12] = ud.x + vd.x; h[13] = ud.y + vd.y; h[14] = ud.z + vd.z; h[15] = ud.w + vd.w;
#pragma unroll
  for (int i = 0; i < 16; ++i) h[i] = fmaxf(a1v[i] * h[i] + c1v[i], 0.f);
#pragma unroll
  for (int i = 0; i < 8; ++i) { fa0[i] = f2bf(h[i]); fa1[i] = f2bf(h[8 + i]); }
}

// ---------------- K4: BN2 stats via MFMA ----------------
__global__ __launch_bounds__(256) void k_stats2(const float* __restrict__ U,
                                                const float* __restrict__ V,
                                                const int* __restrict__ idx,
                                                const float* __restrict__ a1,
                                                const float* __restrict__ c1,
                                                const float* __restrict__ W2,
                                                const float* __restrict__ b2,
                                                float* __restrict__ part) {
  int t = threadIdx.x;
  int l = t & 63, w = t >> 6;
  int g = l >> 4, r = l & 15;
  int b = blockIdx.x >> 9;
  int n0 = (blockIdx.x & 511) << 6;
  size_t bbase = (size_t)b * Nn;

  // B-frags: B[k=o][col=p], lane: col = r, k = 8g+i (+32*hh)
  short8 bw[4][2];
#pragma unroll
  for (int tp = 0; tp < 4; ++tp)
#pragma unroll
    for (int hh = 0; hh < 2; ++hh)
#pragma unroll
      for (int i = 0; i < 8; ++i)
        bw[tp][hh][i] = f2bf(W2[(16 * tp + r) * 64 + 32 * hh + 8 * g + i]);

  float a1v[16], c1v[16];
#pragma unroll
  for (int i = 0; i < 8; ++i) {
    a1v[i] = a1[8 * g + i];          c1v[i] = c1[8 * g + i];
    a1v[8 + i] = a1[32 + 8 * g + i]; c1v[8 + i] = c1[32 + 8 * g + i];
  }
  float b2t[4];
#pragma unroll
  for (int tp = 0; tp < 4; ++tp) b2t[tp] = b2[16 * tp + r];

  float sa[4] = {0.f, 0.f, 0.f, 0.f}, qa[4] = {0.f, 0.f, 0.f, 0.f};
  for (int pt = 0; pt < 16; ++pt) {
    size_t bnP = bbase + n0 + w * 16 + pt;
    short8 fa0, fa1;
    build_frags(U, V, idx, bnP, bbase, g, r, a1v, c1v, fa0, fa1);
#pragma unroll
    for (int tp = 0; tp < 4; ++tp) {
      floatx4 acc = {b2t[tp], b2t[tp], b2t[tp], b2t[tp]};
      acc = __builtin_amdgcn_mfma_f32_16x16x32_bf16(fa0, bw[tp][0], acc, 0, 0, 0);
      acc = __builtin_amdgcn_mfma_f32_16x16x32_bf16(fa1, bw[tp][1], acc, 0, 0, 0);
#pragma unroll
      for (int rg = 0; rg < 4; ++rg) { float h2 = acc[rg]; sa[tp] += h2; qa[tp] += h2 * h2; }
    }
  }
#pragma unroll
  for (int tp = 0; tp < 4; ++tp) {
    sa[tp] += __shfl_xor(sa[tp], 16); sa[tp] += __shfl_xor(sa[tp], 32);
    qa[tp] += __shfl_xor(qa[tp], 16); qa[tp] += __shfl_xor(qa[tp], 32);
  }
  __shared__ float sred[4][64], qred[4][64];
  if (g == 0) {
#pragma unroll
    for (int tp = 0; tp < 4; ++tp) { sred[w][tp * 16 + r] = sa[tp]; qred[w][tp * 16 + r] = qa[tp]; }
  }
  __syncthreads();
  if (w == 0) {
    float s = sred[0][l] + sred[1][l] + sred[2][l] + sred[3][l];
    float q = qred[0][l] + qred[1][l] + qred[2][l] + qred[3][l];
    part[(size_t)blockIdx.x * 128 + l] = s;
    part[(size_t)blockIdx.x * 128 + 64 + l] = q;
  }
}

// ---------------- reduce partials + finalize BN2 ----------------
__global__ void k_red2(const float* __restrict__ part, int nblk,
                       const float* __restrict__ g2, const float* __restrict__ be2,
                       float* __restrict__ a2, float* __restrict__ c2) {
  int t = threadIdx.x;
  int p = t & 63, q4 = t >> 6;
  float s = 0.f, q = 0.f;
  for (int blk = q4; blk < nblk; blk += 4) {
    s += part[(size_t)blk * 128 + p];
    q += part[(size_t)blk * 128 + 64 + p];
  }
  __shared__ float ss[4][64], qq[4][64];
  ss[q4][p] = s; qq[q4][p] = q;
  __syncthreads();
  if (t < 64) {
    s = ss[0][t] + ss[1][t] + ss[2][t] + ss[3][t];
    q = qq[0][t] + qq[1][t] + qq[2][t] + qq[3][t];
    float mean = s / TOTF;
    float var = q / TOTF - mean * mean;
    float av = g2[t] / sqrtf(var + EPSV);
    a2[t] = av;
    c2[t] = be2[t] - mean * av;
  }
}

// ---------------- K6: final output via MFMA ----------------
__global__ __launch_bounds__(256) void k_final(const float* __restrict__ U,
                                               const float* __restrict__ V,
                                               const int* __restrict__ idx,
                                               const float* __restrict__ a1,
                                               const float* __restrict__ c1,
                                               const float* __restrict__ W2,
                                               const float* __restrict__ b2,
                                               const float* __restrict__ a2,
                                               const float* __restrict__ c2,
                                               float* __restrict__ out) {
  __shared__ float om[64][65];
  int t = threadIdx.x;
  int l = t & 63, w = t >> 6;
  int g = l >> 4, r = l & 15;
  int b = blockIdx.x >> 9;
  int n0 = (blockIdx.x & 511) << 6;
  size_t bbase = (size_t)b * Nn;

  short8 bw[4][2];
#pragma unroll
  for (int tp = 0; tp < 4; ++tp)
#pragma unroll
    for (int hh = 0; hh < 2; ++hh)
#pragma unroll
      for (int i = 0; i < 8; ++i)
        bw[tp][hh][i] = f2bf(W2[(16 * tp + r) * 64 + 32 * hh + 8 * g + i]);

  float a1v[16], c1v[16];
#pragma unroll
  for (int i = 0; i < 8; ++i) {
    a1v[i] = a1[8 * g + i];          c1v[i] = c1[8 * g + i];
    a1v[8 + i] = a1[32 + 8 * g + i]; c1v[8 + i] = c1[32 + 8 * g + i];
  }
  float b2t[4], a2t[4], c2t[4];
#pragma unroll
  for (int tp = 0; tp < 4; ++tp) {
    b2t[tp] = b2[16 * tp + r];
    a2t[tp] = a2[16 * tp + r];
    c2t[tp] = c2[16 * tp + r];
  }

  for (int pt = 0; pt < 16; ++pt) {
    size_t bnP = bbase + n0 + w * 16 + pt;
    short8 fa0, fa1;
    build_frags(U, V, idx, bnP, bbase, g, r, a1v, c1v, fa0, fa1);
#pragma unroll
    for (int tp = 0; tp < 4; ++tp) {
      floatx4 acc = {b2t[tp], b2t[tp], b2t[tp], b2t[tp]};
      acc = __builtin_amdgcn_mfma_f32_16x16x32_bf16(fa0, bw[tp][0], acc, 0, 0, 0);
      acc = __builtin_amdgcn_mfma_f32_16x16x32_bf16(fa1, bw[tp][1], acc, 0, 0, 0);
      float mm = 0.f;  // relu output >= 0
#pragma unroll
      for (int rg = 0; rg < 4; ++rg)
        mm = fmaxf(mm, fmaxf(a2t[tp] * acc[rg] + c2t[tp], 0.f));
      mm = fmaxf(mm, __shfl_xor(mm, 16));
      mm = fmaxf(mm, __shfl_xor(mm, 32));
      if (g == 0) om[tp * 16 + r][w * 16 + pt] = mm;
    }
  }
  __syncthreads();
  for (int i = t; i < 4096; i += 256) {
    int p = i >> 6, pc = i & 63;
    out[((size_t)b * 64 + p) * Nn + n0 + pc] = om[p][pc];
  }
}

extern "C" void kernel_launch(void* const* d_in, const int* in_sizes, int n_in,
                              void* d_out, int out_size, void* d_ws, size_t ws_size,
                              hipStream_t stream) {
  const float* x   = (const float*)d_in[0];
  const int*   idx = (const int*)d_in[1];
  const float* W1  = (const float*)d_in[2];
  const float* b1  = (const float*)d_in[3];
  const float* g1  = (const float*)d_in[4];
  const float* be1 = (const float*)d_in[5];
  const float* W2  = (const float*)d_in[6];
  const float* b2  = (const float*)d_in[7];
  const float* g2  = (const float*)d_in[8];
  const float* be2 = (const float*)d_in[9];
  float* out = (float*)d_out;

  float* U  = (float*)d_ws;                  // 32 MB
  float* V  = U + (size_t)BN * 64;           // 32 MB
  float* st = V + (size_t)BN * 64;           // stats scratch (512 f32)
  float* s1 = st,       *q1 = st + 64,  *a1 = st + 128, *c1 = st + 192;
  float* a2 = st + 256, *c2 = st + 320;
  float* part = st + 512;                    // 2048*128 f32 = 1 MB

  hipMemsetAsync(st, 0, 512 * sizeof(float), stream);
  k_uv<<<2048, 256, 0, stream>>>(x, W1, b1, U, V);
  k_stats1<<<1024, 256, 0, stream>>>(U, V, idx, s1, q1);
  k_fin<<<1, 64, 0, stream>>>(s1, q1, g1, be1, a1, c1);
  k_stats2<<<2048, 256, 0, stream>>>(U, V, idx, a1, c1, W2, b2, part);
  k_red2<<<1, 256, 0, stream>>>(part, 2048, g2, be2, a2, c2);
  k_final<<<2048, 256, 0, stream>>>(U, V, idx, a1, c1, W2, b2, a2, c2, out);
}

// Round 3
// 278.261 us; speedup vs baseline: 3.6559x; 1.6744x over previous
//
#include <hip/hip_runtime.h>
#include <math.h>

// EdgeConv: B=4, C=64, N=32768, k=16, O=64
// h1[b,n,k,o] = U[b,n,o] + V[b,idx[b,n,k],o]
//   U = (W1[:, :64] - W1[:, 64:]) @ x + b1
//   V = W1[:, 64:] @ x
// BN affine given stats: relu(a*h + c).  Layer 2 via bf16 MFMA 16x16x32.
// k_main fuses: gather -> BN1+relu -> MFMA -> {BN2 stats, max_k h2 -> Mx}.
// k_out applies BN2+relu to Mx (monotone since a2=g2*rsqrt(var+eps)>0 here)
// and writes the transposed output.

#define EPSV 1e-5f
constexpr int Cc = 64;
constexpr int Nn = 32768;
constexpr int BN = 131072;                     // B*N
constexpr float TOTF = 2097152.0f;             // B*N*k

typedef __attribute__((ext_vector_type(8))) short short8;
typedef __attribute__((ext_vector_type(4))) float floatx4;

__device__ __forceinline__ short f2bf(float f) {
  __bf16 b = (__bf16)f;                        // RNE fptrunc, HW-loweable
  return __builtin_bit_cast(short, b);
}

// ---------------- K1: U,V precompute ----------------
__global__ __launch_bounds__(256) void k_uv(const float* __restrict__ x,
                                            const float* __restrict__ W1,
                                            const float* __restrict__ b1,
                                            float* __restrict__ U,
                                            float* __restrict__ V) {
  __shared__ __align__(16) float wdT[64][64];
  __shared__ __align__(16) float wbT[64][64];
  __shared__ __align__(16) float xs[64][64];
  int t = threadIdx.x;
  int b = blockIdx.x >> 9;
  int n0 = (blockIdx.x & 511) << 6;

  for (int i = t; i < 4096; i += 256) {
    int o = i & 63, c = i >> 6;
    float wa = W1[o * 128 + c];
    float wb = W1[o * 128 + 64 + c];
    wdT[c][o] = wa - wb;
    wbT[c][o] = wb;
  }
  const float* xb = x + (size_t)b * Cc * Nn + n0;
  for (int i = t; i < 4096; i += 256) {
    int c = i >> 6, p = i & 63;
    xs[c][p] = xb[(size_t)c * Nn + p];
  }
  __syncthreads();

  int lane = t & 63;
  int pg = t >> 6;
  int pbase = pg * 16;
  float bv = b1[lane];
  float u[16], v[16];
#pragma unroll
  for (int j = 0; j < 16; ++j) { u[j] = bv; v[j] = 0.f; }

  for (int c = 0; c < 64; ++c) {
    float wd = wdT[c][lane];
    float wb = wbT[c][lane];
#pragma unroll
    for (int j4 = 0; j4 < 4; ++j4) {
      float4 xq = *(const float4*)&xs[c][pbase + j4 * 4];
      u[j4 * 4 + 0] += wd * xq.x; v[j4 * 4 + 0] += wb * xq.x;
      u[j4 * 4 + 1] += wd * xq.y; v[j4 * 4 + 1] += wb * xq.y;
      u[j4 * 4 + 2] += wd * xq.z; v[j4 * 4 + 2] += wb * xq.z;
      u[j4 * 4 + 3] += wd * xq.w; v[j4 * 4 + 3] += wb * xq.w;
    }
  }
  size_t base = ((size_t)b * Nn + n0 + pbase) * 64 + lane;
#pragma unroll
  for (int j = 0; j < 16; ++j) {
    U[base + (size_t)j * 64] = u[j];
    V[base + (size_t)j * 64] = v[j];
  }
}

// ---------------- K2: BN1 stats (gather) ----------------
__global__ __launch_bounds__(256) void k_stats1(const float* __restrict__ U,
                                                const float* __restrict__ V,
                                                const int* __restrict__ idx,
                                                float* __restrict__ s1,
                                                float* __restrict__ q1) {
  int t = threadIdx.x;
  int lane = t & 63, w = t >> 6;
  float s = 0.f, q = 0.f;
  for (int bn = blockIdx.x * 4 + w; bn < BN; bn += 1024 * 4) {
    int b = bn >> 15;
    float u = U[(size_t)bn * 64 + lane];
    const int* ip = idx + (size_t)bn * 16;
#pragma unroll
    for (int k4 = 0; k4 < 4; ++k4) {
      int4 i4 = ((const int4*)ip)[k4];
      int mm[4] = {i4.x, i4.y, i4.z, i4.w};
#pragma unroll
      for (int j = 0; j < 4; ++j) {
        float v = V[(((size_t)b << 15) + mm[j]) * 64 + lane];
        float h = u + v;
        s += h; q += h * h;
      }
    }
  }
  __shared__ float rs[4][64], rq[4][64];
  rs[w][lane] = s; rq[w][lane] = q;
  __syncthreads();
  if (w == 0) {
    s = rs[0][lane] + rs[1][lane] + rs[2][lane] + rs[3][lane];
    q = rq[0][lane] + rq[1][lane] + rq[2][lane] + rq[3][lane];
    atomicAdd(&s1[lane], s);
    atomicAdd(&q1[lane], q);
  }
}

// ---------------- finalize BN stats -> affine ----------------
__global__ void k_fin(const float* __restrict__ s, const float* __restrict__ q,
                      const float* __restrict__ g, const float* __restrict__ be,
                      float* __restrict__ a, float* __restrict__ c) {
  int o = threadIdx.x;
  float mean = s[o] / TOTF;
  float var = q[o] / TOTF - mean * mean;
  float av = g[o] / sqrtf(var + EPSV);
  a[o] = av;
  c[o] = be[o] - mean * av;
}

// -------- frag builder: gather U+V, BN1+relu, pack bf16 A-frags --------
__device__ __forceinline__ void build_frags(const float* __restrict__ U,
                                            const float* __restrict__ V,
                                            const int* __restrict__ idx,
                                            size_t bnP, size_t bbase,
                                            int g, int r,
                                            const float* a1v, const float* c1v,
                                            short8& fa0, short8& fa1) {
  int j = idx[bnP * 16 + r];
  const float* vp = V + (bbase + (size_t)j) * 64;
  const float* up = U + bnP * 64;
  int o0 = g * 8;
  float4 va = *(const float4*)(vp + o0);
  float4 vb = *(const float4*)(vp + o0 + 4);
  float4 vc = *(const float4*)(vp + o0 + 32);
  float4 vd = *(const float4*)(vp + o0 + 36);
  float4 ua = *(const float4*)(up + o0);
  float4 ub = *(const float4*)(up + o0 + 4);
  float4 uc = *(const float4*)(up + o0 + 32);
  float4 ud = *(const float4*)(up + o0 + 36);
  float h[16];
  h[0] = ua.x + va.x;  h[1] = ua.y + va.y;  h[2] = ua.z + va.z;  h[3] = ua.w + va.w;
  h[4] = ub.x + vb.x;  h[5] = ub.y + vb.y;  h[6] = ub.z + vb.z;  h[7] = ub.w + vb.w;
  h[8] = uc.x + vc.x;  h[9] = uc.y + vc.y;  h[10] = uc.z + vc.z; h[11] = uc.w + vc.w;
  h[12] = ud.x + vd.x; h[13] = ud.y + vd.y; h[14] = ud.z + vd.z; h[15] = ud.w + vd.w;
#pragma unroll
  for (int i = 0; i < 16; ++i) h[i] = fmaxf(a1v[i] * h[i] + c1v[i], 0.f);
#pragma unroll
  for (int i = 0; i < 8; ++i) { fa0[i] = f2bf(h[i]); fa1[i] = f2bf(h[8 + i]); }
}

// -------- K4: fused gather -> MFMA -> {BN2 stats, per-point max} --------
__global__ __launch_bounds__(256) void k_main(const float* __restrict__ U,
                                              const float* __restrict__ V,
                                              const int* __restrict__ idx,
                                              const float* __restrict__ a1,
                                              const float* __restrict__ c1,
                                              const float* __restrict__ W2,
                                              const float* __restrict__ b2,
                                              float* __restrict__ s2,
                                              float* __restrict__ q2,
                                              float* __restrict__ Mx) {
  __shared__ __align__(16) float mx_lds[64][64];
  __shared__ float sred[4][64], qred[4][64];
  int t = threadIdx.x;
  int l = t & 63, w = t >> 6;
  int g = l >> 4, r = l & 15;
  int b = blockIdx.x >> 9;
  int n0 = (blockIdx.x & 511) << 6;
  size_t bbase = (size_t)b * Nn;

  // B-frags: B[k=o][col=p], lane: col = r, k = 8g+i (+32*hh)
  short8 bw[4][2];
#pragma unroll
  for (int tp = 0; tp < 4; ++tp)
#pragma unroll
    for (int hh = 0; hh < 2; ++hh)
#pragma unroll
      for (int i = 0; i < 8; ++i)
        bw[tp][hh][i] = f2bf(W2[(16 * tp + r) * 64 + 32 * hh + 8 * g + i]);

  float a1v[16], c1v[16];
#pragma unroll
  for (int i = 0; i < 8; ++i) {
    a1v[i] = a1[8 * g + i];          c1v[i] = c1[8 * g + i];
    a1v[8 + i] = a1[32 + 8 * g + i]; c1v[8 + i] = c1[32 + 8 * g + i];
  }
  float b2t[4];
#pragma unroll
  for (int tp = 0; tp < 4; ++tp) b2t[tp] = b2[16 * tp + r];

  float sa[4] = {0.f, 0.f, 0.f, 0.f}, qa[4] = {0.f, 0.f, 0.f, 0.f};
  for (int pt = 0; pt < 16; ++pt) {
    size_t bnP = bbase + n0 + w * 16 + pt;
    short8 fa0, fa1;
    build_frags(U, V, idx, bnP, bbase, g, r, a1v, c1v, fa0, fa1);
#pragma unroll
    for (int tp = 0; tp < 4; ++tp) {
      floatx4 acc = {b2t[tp], b2t[tp], b2t[tp], b2t[tp]};
      acc = __builtin_amdgcn_mfma_f32_16x16x32_bf16(fa0, bw[tp][0], acc, 0, 0, 0);
      acc = __builtin_amdgcn_mfma_f32_16x16x32_bf16(fa1, bw[tp][1], acc, 0, 0, 0);
      float mm = -3.4e38f;
#pragma unroll
      for (int rg = 0; rg < 4; ++rg) {
        float h2 = acc[rg];
        sa[tp] += h2; qa[tp] += h2 * h2;
        mm = fmaxf(mm, h2);
      }
      mm = fmaxf(mm, __shfl_xor(mm, 16));
      mm = fmaxf(mm, __shfl_xor(mm, 32));
      if (g == 0) mx_lds[w * 16 + pt][tp * 16 + r] = mm;
    }
  }
  // stats reduce: over g (shfl), then over waves (LDS), then atomic
#pragma unroll
  for (int tp = 0; tp < 4; ++tp) {
    sa[tp] += __shfl_xor(sa[tp], 16); sa[tp] += __shfl_xor(sa[tp], 32);
    qa[tp] += __shfl_xor(qa[tp], 16); qa[tp] += __shfl_xor(qa[tp], 32);
  }
  if (g == 0) {
#pragma unroll
    for (int tp = 0; tp < 4; ++tp) { sred[w][tp * 16 + r] = sa[tp]; qred[w][tp * 16 + r] = qa[tp]; }
  }
  __syncthreads();
  if (w == 0) {
    float s = sred[0][l] + sred[1][l] + sred[2][l] + sred[3][l];
    float q = qred[0][l] + qred[1][l] + qred[2][l] + qred[3][l];
    atomicAdd(&s2[l], s);
    atomicAdd(&q2[l], q);
  }
  // write Mx tile (contiguous, coalesced float4)
  float4* dst = (float4*)(Mx + (bbase + n0) * 64);
  const float4* src = (const float4*)mx_lds;
  for (int i = t; i < 1024; i += 256) dst[i] = src[i];
}

// -------- K6: BN2+relu on Mx, transposed write --------
__global__ __launch_bounds__(256) void k_out(const float* __restrict__ Mx,
                                             const float* __restrict__ a2,
                                             const float* __restrict__ c2,
                                             float* __restrict__ out) {
  __shared__ float om[64][65];
  __shared__ float a2s[64], c2s[64];
  int t = threadIdx.x;
  int b = blockIdx.x >> 9;
  int n0 = (blockIdx.x & 511) << 6;
  if (t < 64) { a2s[t] = a2[t]; c2s[t] = c2[t]; }
  __syncthreads();
  const float4* src = (const float4*)(Mx + ((size_t)b * Nn + n0) * 64);
  for (int i = t; i < 1024; i += 256) {
    float4 v4 = src[i];
    int ptl = i >> 4, p0 = (i & 15) * 4;
    float vv[4] = {v4.x, v4.y, v4.z, v4.w};
#pragma unroll
    for (int j = 0; j < 4; ++j) {
      int p = p0 + j;
      om[p][ptl] = fmaxf(a2s[p] * vv[j] + c2s[p], 0.f);
    }
  }
  __syncthreads();
  for (int i = t; i < 1024; i += 256) {
    int p = i >> 4, nn4 = (i & 15) * 4;
    float4 o4 = {om[p][nn4], om[p][nn4 + 1], om[p][nn4 + 2], om[p][nn4 + 3]};
    *(float4*)&out[((size_t)b * 64 + p) * Nn + n0 + nn4] = o4;
  }
}

extern "C" void kernel_launch(void* const* d_in, const int* in_sizes, int n_in,
                              void* d_out, int out_size, void* d_ws, size_t ws_size,
                              hipStream_t stream) {
  const float* x   = (const float*)d_in[0];
  const int*   idx = (const int*)d_in[1];
  const float* W1  = (const float*)d_in[2];
  const float* b1  = (const float*)d_in[3];
  const float* g1  = (const float*)d_in[4];
  const float* be1 = (const float*)d_in[5];
  const float* W2  = (const float*)d_in[6];
  const float* b2  = (const float*)d_in[7];
  const float* g2  = (const float*)d_in[8];
  const float* be2 = (const float*)d_in[9];
  float* out = (float*)d_out;

  float* U  = (float*)d_ws;                    // 32 MB
  float* V  = U + (size_t)BN * 64;             // 32 MB
  float* st = V + (size_t)BN * 64;             // 512 floats
  float* s1 = st,       *q1 = st + 64,  *a1 = st + 128, *c1 = st + 192;
  float* s2 = st + 256, *q2 = st + 320, *a2 = st + 384, *c2 = st + 448;
  float* Mx = st + 512;                        // 32 MB

  hipMemsetAsync(st, 0, 512 * sizeof(float), stream);
  k_uv<<<2048, 256, 0, stream>>>(x, W1, b1, U, V);
  k_stats1<<<1024, 256, 0, stream>>>(U, V, idx, s1, q1);
  k_fin<<<1, 64, 0, stream>>>(s1, q1, g1, be1, a1, c1);
  k_main<<<2048, 256, 0, stream>>>(U, V, idx, a1, c1, W2, b2, s2, q2, Mx);
  k_fin<<<1, 64, 0, stream>>>(s2, q2, g2, be2, a2, c2);
  k_out<<<2048, 256, 0, stream>>>(Mx, a2, c2, out);
}